// Round 2
// baseline (759.809 us; speedup 1.0000x reference)
//
#include <hip/hip_runtime.h>

#define NN 100000
#define NE 1600000
#define FIN 256
#define FH 64
#define FC 16

// ---- edge-index dtype robustness: int64 vs int32 detection -----------------
__global__ void detect_k(const int* __restrict__ ei, int* __restrict__ flag) {
    if (threadIdx.x == 0 && blockIdx.x == 0) {
        int z = (ei[1] == 0) & (ei[3] == 0) & (ei[5] == 0) & (ei[7] == 0);
        *flag = z;   // 1 => int64 layout, 0 => int32 layout
    }
}

__device__ __forceinline__ int eidx(const int* __restrict__ ei, int f, int pos) {
    return f ? ei[2 * pos] : ei[pos];
}

// ---- degree histogram (dst side; self-loop accounted as +1 in dinv) --------
__global__ void count_k(const int* __restrict__ ei, const int* __restrict__ flag,
                        int* __restrict__ deg) {
    int e = blockIdx.x * 256 + threadIdx.x;
    if (e >= NE) return;
    int f = *flag;
    int d = eidx(ei, f, NE + e);
    atomicAdd(&deg[d], 1);
}

__global__ void dinv_k(const int* __restrict__ deg, float* __restrict__ dinv) {
    int i = blockIdx.x * 256 + threadIdx.x;
    if (i < NN) dinv[i] = rsqrtf((float)(deg[i] + 1));  // +1 self-loop
}

// ---- exclusive scan of deg -> row_start (and cursor copy) ------------------
// Single block, 1024 threads, ~98 elems/thread + Hillis-Steele over chunk sums.
// cursor MAY alias deg (deg value read before cursor write at same index).
__global__ __launch_bounds__(1024) void scan_k(const int* __restrict__ deg,
                                               int* __restrict__ row_start,
                                               int* __restrict__ cursor) {
    __shared__ int sums[1024];
    const int t = threadIdx.x;
    const int CH = (NN + 1023) / 1024;   // 98
    int lo = t * CH;
    int hi = lo + CH; if (hi > NN) hi = NN;
    int s = 0;
    for (int i = lo; i < hi; i++) s += deg[i];
    sums[t] = s;
    __syncthreads();
    for (int off = 1; off < 1024; off <<= 1) {
        int u = (t >= off) ? sums[t - off] : 0;
        __syncthreads();
        sums[t] += u;
        __syncthreads();
    }
    int run = sums[t] - s;               // exclusive prefix of this chunk
    for (int i = lo; i < hi; i++) {
        int dv = deg[i];                 // read BEFORE cursor write (aliasing-safe)
        row_start[i] = run;
        cursor[i] = run;
        run += dv;
    }
    if (t == 1023) row_start[NN] = run;  // == NE
}

// ---- CSR fill: csr[pos] = src, pos from per-dst cursor ---------------------
__global__ void fill_k(const int* __restrict__ ei, const int* __restrict__ flag,
                       int* __restrict__ cursor, int* __restrict__ csr) {
    int e = blockIdx.x * 256 + threadIdx.x;
    if (e >= NE) return;
    int f = *flag;
    int s = eidx(ei, f, e);
    int d = eidx(ei, f, NE + e);
    int pos = atomicAdd(&cursor[d], 1);
    csr[pos] = s;
}

// ---- GEMM1: h1[NN][64] = x[NN][256] @ W1[256][64] --------------------------
__global__ __launch_bounds__(256) void gemm1_k(const float* __restrict__ x,
                                               const float* __restrict__ W,
                                               float* __restrict__ h) {
    __shared__ float As[64][68];
    __shared__ float Bs[64][64];
    const int t = threadIdx.x;
    const int r0 = blockIdx.x * 64;
    const int tx4 = (t & 15) * 4;
    const int ty4 = (t >> 4) * 4;
    const int lrow = t >> 4;
    const int lkf = (t & 15) * 4;

    float acc[4][4] = {};

    for (int k0 = 0; k0 < FIN; k0 += 64) {
        #pragma unroll
        for (int i = 0; i < 4; i++) {
            int row = lrow + 16 * i;
            int gr = r0 + row;
            float4 v = make_float4(0.f, 0.f, 0.f, 0.f);
            if (gr < NN) v = *(const float4*)&x[gr * FIN + k0 + lkf];
            As[lkf + 0][row] = v.x;
            As[lkf + 1][row] = v.y;
            As[lkf + 2][row] = v.z;
            As[lkf + 3][row] = v.w;
            float4 w = *(const float4*)&W[(k0 + row) * FH + lkf];
            *(float4*)&Bs[row][lkf] = w;
        }
        __syncthreads();
        #pragma unroll 8
        for (int kk = 0; kk < 64; kk++) {
            float4 a = *(const float4*)&As[kk][ty4];
            float4 b = *(const float4*)&Bs[kk][tx4];
            float av[4] = {a.x, a.y, a.z, a.w};
            float bv[4] = {b.x, b.y, b.z, b.w};
            #pragma unroll
            for (int i2 = 0; i2 < 4; i2++)
                #pragma unroll
                for (int j2 = 0; j2 < 4; j2++)
                    acc[i2][j2] = fmaf(av[i2], bv[j2], acc[i2][j2]);
        }
        __syncthreads();
    }
    #pragma unroll
    for (int i2 = 0; i2 < 4; i2++) {
        int r = r0 + ty4 + i2;
        if (r < NN)
            *(float4*)&h[r * FH + tx4] =
                make_float4(acc[i2][0], acc[i2][1], acc[i2][2], acc[i2][3]);
    }
}

// ---- aggregate layer1: one wave per node, lane = feature -------------------
// out[n] = dinv[n] * ( sum_src dinv[src]*h1[src] + dinv[n]*h1[n] ) + b1
__global__ __launch_bounds__(256) void agg1_k(const int* __restrict__ csr,
                                              const int* __restrict__ row_start,
                                              const float* __restrict__ h1,
                                              const float* __restrict__ dinv,
                                              const float* __restrict__ b1,
                                              float* __restrict__ agg) {
    int n = blockIdx.x * 4 + (threadIdx.x >> 6);
    int lane = threadIdx.x & 63;
    if (n >= NN) return;
    int s0 = row_start[n], s1 = row_start[n + 1];
    float acc = 0.f;
    for (int j0 = s0; j0 < s1; j0 += 64) {
        int idx = j0 + lane;
        int sl = 0; float wl = 0.f;
        if (idx < s1) { sl = csr[idx]; wl = dinv[sl]; }   // 64 edges preloaded/lane
        int cnt = s1 - j0; if (cnt > 64) cnt = 64;
        for (int j = 0; j < cnt; j++) {
            int   s = __shfl(sl, j, 64);
            float w = __shfl(wl, j, 64);
            acc = fmaf(h1[s * FH + lane], w, acc);        // coalesced 256B row read
        }
    }
    float dn = dinv[n];
    acc = fmaf(h1[n * FH + lane], dn, acc);               // self-loop
    agg[n * FH + lane] = fmaf(acc, dn, b1[lane]);
}

// ---- GEMM2 + relu: h2[NN][16] = relu(agg1) @ W2[64][16] -------------------
__global__ __launch_bounds__(192) void gemm2_k(const float* __restrict__ agg,
                                               const float* __restrict__ W2,
                                               float* __restrict__ h2) {
    __shared__ float a_lds[192 * 65];
    const int t = threadIdx.x;
    const int r0 = blockIdx.x * 192;
    #pragma unroll
    for (int i = 0; i < 16; i++) {
        int fidx = t + 192 * i;
        int row = fidx >> 4, kf = (fidx & 15) * 4;
        int gr = r0 + row;
        float4 v = make_float4(0.f, 0.f, 0.f, 0.f);
        if (gr < NN) v = *(const float4*)&agg[gr * FH + kf];
        v.x = fmaxf(v.x, 0.f); v.y = fmaxf(v.y, 0.f);
        v.z = fmaxf(v.z, 0.f); v.w = fmaxf(v.w, 0.f);
        a_lds[row * 65 + kf + 0] = v.x;
        a_lds[row * 65 + kf + 1] = v.y;
        a_lds[row * 65 + kf + 2] = v.z;
        a_lds[row * 65 + kf + 3] = v.w;
    }
    __syncthreads();
    float acc[FC] = {};
    #pragma unroll 4
    for (int k = 0; k < FH; k++) {
        float a = a_lds[t * 65 + k];
        #pragma unroll
        for (int c = 0; c < FC; c++)
            acc[c] = fmaf(a, W2[k * FC + c], acc[c]);
    }
    int r = r0 + t;
    if (r < NN) {
        #pragma unroll
        for (int q = 0; q < 4; q++)
            *(float4*)&h2[r * FC + 4 * q] =
                make_float4(acc[4*q], acc[4*q+1], acc[4*q+2], acc[4*q+3]);
    }
}

// ---- aggregate layer2: 16-lane subgroup per node ---------------------------
__global__ __launch_bounds__(256) void agg2_k(const int* __restrict__ csr,
                                              const int* __restrict__ row_start,
                                              const float* __restrict__ h2,
                                              const float* __restrict__ dinv,
                                              const float* __restrict__ b2,
                                              float* __restrict__ out) {
    int n = blockIdx.x * 16 + (threadIdx.x >> 4);
    int l16 = threadIdx.x & 15;
    int base = threadIdx.x & 48;      // subgroup base lane within wave
    if (n >= NN) return;
    int s0 = row_start[n], s1 = row_start[n + 1];
    float acc = 0.f;
    for (int j0 = s0; j0 < s1; j0 += 16) {
        int idx = j0 + l16;
        int sl = 0; float wl = 0.f;
        if (idx < s1) { sl = csr[idx]; wl = dinv[sl]; }
        int cnt = s1 - j0; if (cnt > 16) cnt = 16;
        for (int j = 0; j < cnt; j++) {
            int   s = __shfl(sl, base + j, 64);
            float w = __shfl(wl, base + j, 64);
            acc = fmaf(h2[s * FC + l16], w, acc);
        }
    }
    float dn = dinv[n];
    acc = fmaf(h2[n * FC + l16], dn, acc);
    out[n * FC + l16] = fmaf(acc, dn, b2[l16]);
}

extern "C" void kernel_launch(void* const* d_in, const int* in_sizes, int n_in,
                              void* d_out, int out_size, void* d_ws, size_t ws_size,
                              hipStream_t stream) {
    const float* x  = (const float*)d_in[0];
    const int*   ei = (const int*)d_in[1];
    const float* W1 = (const float*)d_in[2];
    const float* b1 = (const float*)d_in[3];
    const float* W2 = (const float*)d_in[4];
    const float* b2 = (const float*)d_in[5];
    float* out = (float*)d_out;

    char* ws = (char*)d_ws;
    int*   deg       = (int*)(ws + 0);                     // 400 KB (cursor aliases)
    int*   cursor    = deg;                                // alias — scan handles it
    int*   row_start = (int*)(ws + 512 * 1024);            // 400 KB + 4
    float* dinv      = (float*)(ws + 1024 * 1024);         // 400 KB
    int*   flag      = (int*)(ws + 1536 * 1024);           // 4 B
    int*   csr       = (int*)(ws + 2ull * 1024 * 1024);    // 6.4 MB
    float* h1        = (float*)(ws + 9ull * 1024 * 1024);  // 25.6 MB
    float* agg1      = (float*)(ws + 35ull * 1024 * 1024); // 25.6 MB
    float* h2        = h1;                                 // alias: h1 dead after agg1_k

    detect_k<<<1, 64, 0, stream>>>(ei, flag);
    hipMemsetAsync(deg, 0, NN * sizeof(int), stream);
    count_k<<<(NE + 255) / 256, 256, 0, stream>>>(ei, flag, deg);
    dinv_k<<<(NN + 255) / 256, 256, 0, stream>>>(deg, dinv);
    scan_k<<<1, 1024, 0, stream>>>(deg, row_start, cursor);
    fill_k<<<(NE + 255) / 256, 256, 0, stream>>>(ei, flag, cursor, csr);

    gemm1_k<<<(NN + 63) / 64, 256, 0, stream>>>(x, W1, h1);
    agg1_k<<<(NN + 3) / 4, 256, 0, stream>>>(csr, row_start, h1, dinv, b1, agg1);

    gemm2_k<<<(NN + 191) / 192, 192, 0, stream>>>(agg1, W2, h2);
    agg2_k<<<(NN + 15) / 16, 256, 0, stream>>>(csr, row_start, h2, dinv, b2, out);
}

// Round 3
// 547.426 us; speedup vs baseline: 1.3880x; 1.3880x over previous
//
#include <hip/hip_runtime.h>

#define NN 100000
#define NE 1600000
#define FIN 256
#define FH 64
#define FC 16

#define SCAN_CHUNK 1024
#define NB_SCAN ((NN + SCAN_CHUNK - 1) / SCAN_CHUNK)   // 98

// ---- edge-index dtype robustness: int64 vs int32 detection -----------------
__global__ void detect_k(const int* __restrict__ ei, int* __restrict__ flag) {
    if (threadIdx.x == 0 && blockIdx.x == 0) {
        int z = (ei[1] == 0) & (ei[3] == 0) & (ei[5] == 0) & (ei[7] == 0);
        *flag = z;   // 1 => int64 layout, 0 => int32 layout
    }
}

__device__ __forceinline__ int eidx(const int* __restrict__ ei, int f, int pos) {
    return f ? ei[2 * pos] : ei[pos];
}

// ---- degree histogram (dst side; self-loop accounted as +1 in dinv) --------
__global__ void count_k(const int* __restrict__ ei, const int* __restrict__ flag,
                        int* __restrict__ deg) {
    int e = blockIdx.x * 256 + threadIdx.x;
    if (e >= NE) return;
    int f = *flag;
    int d = eidx(ei, f, NE + e);
    atomicAdd(&deg[d], 1);
}

__global__ void dinv_k(const int* __restrict__ deg, float* __restrict__ dinv) {
    int i = blockIdx.x * 256 + threadIdx.x;
    if (i < NN) dinv[i] = rsqrtf((float)(deg[i] + 1));  // +1 self-loop
}

// ---- multi-block exclusive scan: pass 1, per-block sums --------------------
__global__ __launch_bounds__(256) void scan_sum_k(const int* __restrict__ deg,
                                                  int* __restrict__ partial) {
    __shared__ int red[256];
    int b = blockIdx.x, t = threadIdx.x;
    int base = b * SCAN_CHUNK + t * 4;
    int s = 0;
    #pragma unroll
    for (int i = 0; i < 4; i++) { int idx = base + i; if (idx < NN) s += deg[idx]; }
    red[t] = s;
    __syncthreads();
    for (int off = 128; off > 0; off >>= 1) {
        if (t < off) red[t] += red[t + off];
        __syncthreads();
    }
    if (t == 0) partial[b] = red[0];
}

// ---- pass 2: single small block exclusive-scans the partials ---------------
__global__ __launch_bounds__(128) void scan_part_k(int* __restrict__ partial) {
    __shared__ int s[128];
    int t = threadIdx.x;
    int v = (t < NB_SCAN) ? partial[t] : 0;
    s[t] = v; __syncthreads();
    for (int off = 1; off < 128; off <<= 1) {
        int u = (t >= off) ? s[t - off] : 0;
        __syncthreads();
        s[t] += u;
        __syncthreads();
    }
    if (t < NB_SCAN) partial[t] = s[t] - v;   // exclusive
}

// ---- pass 3: per-block local scan + offset -> row_start, cursor ------------
__global__ __launch_bounds__(256) void scan_out_k(const int* __restrict__ deg,
                                                  const int* __restrict__ partial,
                                                  int* __restrict__ row_start,
                                                  int* __restrict__ cursor) {
    __shared__ int s[256];
    int b = blockIdx.x, t = threadIdx.x;
    int base = b * SCAN_CHUNK + t * 4;
    int v[4]; int sum = 0;
    #pragma unroll
    for (int i = 0; i < 4; i++) {
        int idx = base + i;
        v[i] = (idx < NN) ? deg[idx] : 0;
        sum += v[i];
    }
    s[t] = sum; __syncthreads();
    for (int off = 1; off < 256; off <<= 1) {
        int u = (t >= off) ? s[t - off] : 0;
        __syncthreads();
        s[t] += u;
        __syncthreads();
    }
    int run = partial[b] + s[t] - sum;        // exclusive prefix for this thread
    #pragma unroll
    for (int i = 0; i < 4; i++) {
        int idx = base + i;
        if (idx < NN) {
            row_start[idx] = run;
            cursor[idx] = run;
            run += v[i];
            if (idx == NN - 1) row_start[NN] = run;   // == NE
        }
    }
}

// ---- CSR fill: csr[pos] = src, pos from per-dst cursor ---------------------
__global__ void fill_k(const int* __restrict__ ei, const int* __restrict__ flag,
                       int* __restrict__ cursor, int* __restrict__ csr) {
    int e = blockIdx.x * 256 + threadIdx.x;
    if (e >= NE) return;
    int f = *flag;
    int s = eidx(ei, f, e);
    int d = eidx(ei, f, NE + e);
    int pos = atomicAdd(&cursor[d], 1);
    csr[pos] = s;
}

// ---- GEMM1: h1[NN][64] = x[NN][256] @ W1[256][64] --------------------------
__global__ __launch_bounds__(256) void gemm1_k(const float* __restrict__ x,
                                               const float* __restrict__ W,
                                               float* __restrict__ h) {
    __shared__ float As[64][68];
    __shared__ float Bs[64][64];
    const int t = threadIdx.x;
    const int r0 = blockIdx.x * 64;
    const int tx4 = (t & 15) * 4;
    const int ty4 = (t >> 4) * 4;
    const int lrow = t >> 4;
    const int lkf = (t & 15) * 4;

    float acc[4][4] = {};

    for (int k0 = 0; k0 < FIN; k0 += 64) {
        #pragma unroll
        for (int i = 0; i < 4; i++) {
            int row = lrow + 16 * i;
            int gr = r0 + row;
            float4 v = make_float4(0.f, 0.f, 0.f, 0.f);
            if (gr < NN) v = *(const float4*)&x[gr * FIN + k0 + lkf];
            As[lkf + 0][row] = v.x;
            As[lkf + 1][row] = v.y;
            As[lkf + 2][row] = v.z;
            As[lkf + 3][row] = v.w;
            float4 w = *(const float4*)&W[(k0 + row) * FH + lkf];
            *(float4*)&Bs[row][lkf] = w;
        }
        __syncthreads();
        #pragma unroll 8
        for (int kk = 0; kk < 64; kk++) {
            float4 a = *(const float4*)&As[kk][ty4];
            float4 b = *(const float4*)&Bs[kk][tx4];
            float av[4] = {a.x, a.y, a.z, a.w};
            float bv[4] = {b.x, b.y, b.z, b.w};
            #pragma unroll
            for (int i2 = 0; i2 < 4; i2++)
                #pragma unroll
                for (int j2 = 0; j2 < 4; j2++)
                    acc[i2][j2] = fmaf(av[i2], bv[j2], acc[i2][j2]);
        }
        __syncthreads();
    }
    #pragma unroll
    for (int i2 = 0; i2 < 4; i2++) {
        int r = r0 + ty4 + i2;
        if (r < NN)
            *(float4*)&h[r * FH + tx4] =
                make_float4(acc[i2][0], acc[i2][1], acc[i2][2], acc[i2][3]);
    }
}

// ---- aggregate layer1: one wave per node, lane = feature -------------------
__global__ __launch_bounds__(256) void agg1_k(const int* __restrict__ csr,
                                              const int* __restrict__ row_start,
                                              const float* __restrict__ h1,
                                              const float* __restrict__ dinv,
                                              const float* __restrict__ b1,
                                              float* __restrict__ agg) {
    int n = blockIdx.x * 4 + (threadIdx.x >> 6);
    int lane = threadIdx.x & 63;
    if (n >= NN) return;
    int s0 = row_start[n], s1 = row_start[n + 1];
    float acc = 0.f;
    for (int j0 = s0; j0 < s1; j0 += 64) {
        int idx = j0 + lane;
        int sl = 0; float wl = 0.f;
        if (idx < s1) { sl = csr[idx]; wl = dinv[sl]; }
        int cnt = s1 - j0; if (cnt > 64) cnt = 64;
        for (int j = 0; j < cnt; j++) {
            int   s = __shfl(sl, j, 64);
            float w = __shfl(wl, j, 64);
            acc = fmaf(h1[s * FH + lane], w, acc);
        }
    }
    float dn = dinv[n];
    acc = fmaf(h1[n * FH + lane], dn, acc);
    agg[n * FH + lane] = fmaf(acc, dn, b1[lane]);
}

// ---- GEMM2 + relu: h2[NN][16] = relu(agg1) @ W2[64][16] -------------------
__global__ __launch_bounds__(192) void gemm2_k(const float* __restrict__ agg,
                                               const float* __restrict__ W2,
                                               float* __restrict__ h2) {
    __shared__ float a_lds[192 * 65];
    const int t = threadIdx.x;
    const int r0 = blockIdx.x * 192;
    #pragma unroll
    for (int i = 0; i < 16; i++) {
        int fidx = t + 192 * i;
        int row = fidx >> 4, kf = (fidx & 15) * 4;
        int gr = r0 + row;
        float4 v = make_float4(0.f, 0.f, 0.f, 0.f);
        if (gr < NN) v = *(const float4*)&agg[gr * FH + kf];
        v.x = fmaxf(v.x, 0.f); v.y = fmaxf(v.y, 0.f);
        v.z = fmaxf(v.z, 0.f); v.w = fmaxf(v.w, 0.f);
        a_lds[row * 65 + kf + 0] = v.x;
        a_lds[row * 65 + kf + 1] = v.y;
        a_lds[row * 65 + kf + 2] = v.z;
        a_lds[row * 65 + kf + 3] = v.w;
    }
    __syncthreads();
    float acc[FC] = {};
    #pragma unroll 4
    for (int k = 0; k < FH; k++) {
        float a = a_lds[t * 65 + k];
        #pragma unroll
        for (int c = 0; c < FC; c++)
            acc[c] = fmaf(a, W2[k * FC + c], acc[c]);
    }
    int r = r0 + t;
    if (r < NN) {
        #pragma unroll
        for (int q = 0; q < 4; q++)
            *(float4*)&h2[r * FC + 4 * q] =
                make_float4(acc[4*q], acc[4*q+1], acc[4*q+2], acc[4*q+3]);
    }
}

// ---- aggregate layer2: 16-lane subgroup per node ---------------------------
__global__ __launch_bounds__(256) void agg2_k(const int* __restrict__ csr,
                                              const int* __restrict__ row_start,
                                              const float* __restrict__ h2,
                                              const float* __restrict__ dinv,
                                              const float* __restrict__ b2,
                                              float* __restrict__ out) {
    int n = blockIdx.x * 16 + (threadIdx.x >> 4);
    int l16 = threadIdx.x & 15;
    int base = threadIdx.x & 48;
    if (n >= NN) return;
    int s0 = row_start[n], s1 = row_start[n + 1];
    float acc = 0.f;
    for (int j0 = s0; j0 < s1; j0 += 16) {
        int idx = j0 + l16;
        int sl = 0; float wl = 0.f;
        if (idx < s1) { sl = csr[idx]; wl = dinv[sl]; }
        int cnt = s1 - j0; if (cnt > 16) cnt = 16;
        for (int j = 0; j < cnt; j++) {
            int   s = __shfl(sl, base + j, 64);
            float w = __shfl(wl, base + j, 64);
            acc = fmaf(h2[s * FC + l16], w, acc);
        }
    }
    float dn = dinv[n];
    acc = fmaf(h2[n * FC + l16], dn, acc);
    out[n * FC + l16] = fmaf(acc, dn, b2[l16]);
}

extern "C" void kernel_launch(void* const* d_in, const int* in_sizes, int n_in,
                              void* d_out, int out_size, void* d_ws, size_t ws_size,
                              hipStream_t stream) {
    const float* x  = (const float*)d_in[0];
    const int*   ei = (const int*)d_in[1];
    const float* W1 = (const float*)d_in[2];
    const float* b1 = (const float*)d_in[3];
    const float* W2 = (const float*)d_in[4];
    const float* b2 = (const float*)d_in[5];
    float* out = (float*)d_out;

    char* ws = (char*)d_ws;
    int*   deg       = (int*)(ws + 0);                       // 400 KB
    int*   cursor    = (int*)(ws + 512 * 1024);              // 400 KB
    int*   row_start = (int*)(ws + 1024 * 1024);             // 400 KB + 4
    float* dinv      = (float*)(ws + 1536 * 1024);           // 400 KB
    int*   flag      = (int*)(ws + 1984 * 1024);             // 4 B
    int*   partial   = (int*)(ws + 1988 * 1024);             // 392 B
    int*   csr       = (int*)(ws + 2ull * 1024 * 1024);      // 6.4 MB
    float* h1        = (float*)(ws + 9ull * 1024 * 1024);    // 25.6 MB
    float* agg1      = (float*)(ws + 35ull * 1024 * 1024);   // 25.6 MB
    float* h2        = h1;   // alias: h1 dead after agg1_k

    detect_k<<<1, 64, 0, stream>>>(ei, flag);
    hipMemsetAsync(deg, 0, NN * sizeof(int), stream);
    count_k<<<(NE + 255) / 256, 256, 0, stream>>>(ei, flag, deg);
    dinv_k<<<(NN + 255) / 256, 256, 0, stream>>>(deg, dinv);
    scan_sum_k<<<NB_SCAN, 256, 0, stream>>>(deg, partial);
    scan_part_k<<<1, 128, 0, stream>>>(partial);
    scan_out_k<<<NB_SCAN, 256, 0, stream>>>(deg, partial, row_start, cursor);
    fill_k<<<(NE + 255) / 256, 256, 0, stream>>>(ei, flag, cursor, csr);

    gemm1_k<<<(NN + 63) / 64, 256, 0, stream>>>(x, W1, h1);
    agg1_k<<<(NN + 3) / 4, 256, 0, stream>>>(csr, row_start, h1, dinv, b1, agg1);

    gemm2_k<<<(NN + 191) / 192, 192, 0, stream>>>(agg1, W2, h2);
    agg2_k<<<(NN + 15) / 16, 256, 0, stream>>>(csr, row_start, h2, dinv, b2, out);
}

// Round 5
// 423.853 us; speedup vs baseline: 1.7926x; 1.2915x over previous
//
#include <hip/hip_runtime.h>

#define NN 100000
#define NE 1600000
#define FIN 256
#define FH 64
#define FC 16

#define SCAN_CHUNK 1024
#define NB_SCAN ((NN + SCAN_CHUNK - 1) / SCAN_CHUNK)   // 98
#define NSWEEP 4
#define SWEEP_W ((NN + NSWEEP - 1) / NSWEEP)           // 25000

typedef int v4i __attribute__((ext_vector_type(4)));

// ---- edge-index dtype robustness: int64 vs int32 detection -----------------
__global__ void detect_k(const int* __restrict__ ei, int* __restrict__ flag) {
    if (threadIdx.x == 0 && blockIdx.x == 0) {
        int z = (ei[1] == 0) & (ei[3] == 0) & (ei[5] == 0) & (ei[7] == 0);
        *flag = z;   // 1 => int64 layout, 0 => int32 layout
    }
}

__device__ __forceinline__ int eidx(const int* __restrict__ ei, int f, int pos) {
    return f ? ei[2 * pos] : ei[pos];
}

// ---- count + rank + pack: rank[e] = old deg value (atomic order) -----------
__global__ __launch_bounds__(256) void count_k(const int* __restrict__ ei,
                                               const int* __restrict__ flag,
                                               int* __restrict__ deg,
                                               v4i* __restrict__ packed) {
    int e = blockIdx.x * 256 + threadIdx.x;
    if (e >= NE) return;
    int f = *flag;
    int s = eidx(ei, f, e);
    int d = eidx(ei, f, NE + e);
    int r = atomicAdd(&deg[d], 1);
    v4i p; p.x = s; p.y = d; p.z = r; p.w = 0;
    packed[e] = p;
}

__global__ void dinv_k(const int* __restrict__ deg, float* __restrict__ dinv) {
    int i = blockIdx.x * 256 + threadIdx.x;
    if (i < NN) dinv[i] = rsqrtf((float)(deg[i] + 1));  // +1 self-loop
}

// ---- multi-block exclusive scan: pass 1, per-block sums --------------------
__global__ __launch_bounds__(256) void scan_sum_k(const int* __restrict__ deg,
                                                  int* __restrict__ partial) {
    __shared__ int red[256];
    int b = blockIdx.x, t = threadIdx.x;
    int base = b * SCAN_CHUNK + t * 4;
    int s = 0;
    #pragma unroll
    for (int i = 0; i < 4; i++) { int idx = base + i; if (idx < NN) s += deg[idx]; }
    red[t] = s;
    __syncthreads();
    for (int off = 128; off > 0; off >>= 1) {
        if (t < off) red[t] += red[t + off];
        __syncthreads();
    }
    if (t == 0) partial[b] = red[0];
}

// ---- pass 2: single small block exclusive-scans the partials ---------------
__global__ __launch_bounds__(128) void scan_part_k(int* __restrict__ partial) {
    __shared__ int s[128];
    int t = threadIdx.x;
    int v = (t < NB_SCAN) ? partial[t] : 0;
    s[t] = v; __syncthreads();
    for (int off = 1; off < 128; off <<= 1) {
        int u = (t >= off) ? s[t - off] : 0;
        __syncthreads();
        s[t] += u;
        __syncthreads();
    }
    if (t < NB_SCAN) partial[t] = s[t] - v;   // exclusive
}

// ---- pass 3: per-block local scan + offset -> row_start --------------------
__global__ __launch_bounds__(256) void scan_out_k(const int* __restrict__ deg,
                                                  const int* __restrict__ partial,
                                                  int* __restrict__ row_start) {
    __shared__ int s[256];
    int b = blockIdx.x, t = threadIdx.x;
    int base = b * SCAN_CHUNK + t * 4;
    int v[4]; int sum = 0;
    #pragma unroll
    for (int i = 0; i < 4; i++) {
        int idx = base + i;
        v[i] = (idx < NN) ? deg[idx] : 0;
        sum += v[i];
    }
    s[t] = sum; __syncthreads();
    for (int off = 1; off < 256; off <<= 1) {
        int u = (t >= off) ? s[t - off] : 0;
        __syncthreads();
        s[t] += u;
        __syncthreads();
    }
    int run = partial[b] + s[t] - sum;
    #pragma unroll
    for (int i = 0; i < 4; i++) {
        int idx = base + i;
        if (idx < NN) {
            row_start[idx] = run;
            run += v[i];
            if (idx == NN - 1) row_start[NN] = run;   // == NE
        }
    }
}

// ---- CSR fill, dst-range sweep: pure store, no atomic ----------------------
__global__ __launch_bounds__(256) void fill_k(const v4i* __restrict__ packed,
                                              const int* __restrict__ row_start,
                                              int* __restrict__ csr,
                                              int lo, int hi) {
    int e = blockIdx.x * 256 + threadIdx.x;
    if (e >= NE) return;
    v4i p = __builtin_nontemporal_load(&packed[e]);   // (src, dst, rank, 0)
    if (p.y < lo || p.y >= hi) return;
    csr[row_start[p.y] + p.z] = p.x;
}

// ---- GEMM1: h1[NN][64] = x[NN][256] @ W1[256][64] --------------------------
__global__ __launch_bounds__(256) void gemm1_k(const float* __restrict__ x,
                                               const float* __restrict__ W,
                                               float* __restrict__ h) {
    __shared__ float As[64][68];
    __shared__ float Bs[64][64];
    const int t = threadIdx.x;
    const int r0 = blockIdx.x * 64;
    const int tx4 = (t & 15) * 4;
    const int ty4 = (t >> 4) * 4;
    const int lrow = t >> 4;
    const int lkf = (t & 15) * 4;

    float acc[4][4] = {};

    for (int k0 = 0; k0 < FIN; k0 += 64) {
        #pragma unroll
        for (int i = 0; i < 4; i++) {
            int row = lrow + 16 * i;
            int gr = r0 + row;
            float4 v = make_float4(0.f, 0.f, 0.f, 0.f);
            if (gr < NN) v = *(const float4*)&x[gr * FIN + k0 + lkf];
            As[lkf + 0][row] = v.x;
            As[lkf + 1][row] = v.y;
            As[lkf + 2][row] = v.z;
            As[lkf + 3][row] = v.w;
            float4 w = *(const float4*)&W[(k0 + row) * FH + lkf];
            *(float4*)&Bs[row][lkf] = w;
        }
        __syncthreads();
        #pragma unroll 8
        for (int kk = 0; kk < 64; kk++) {
            float4 a = *(const float4*)&As[kk][ty4];
            float4 b = *(const float4*)&Bs[kk][tx4];
            float av[4] = {a.x, a.y, a.z, a.w};
            float bv[4] = {b.x, b.y, b.z, b.w};
            #pragma unroll
            for (int i2 = 0; i2 < 4; i2++)
                #pragma unroll
                for (int j2 = 0; j2 < 4; j2++)
                    acc[i2][j2] = fmaf(av[i2], bv[j2], acc[i2][j2]);
        }
        __syncthreads();
    }
    #pragma unroll
    for (int i2 = 0; i2 < 4; i2++) {
        int r = r0 + ty4 + i2;
        if (r < NN)
            *(float4*)&h[r * FH + tx4] =
                make_float4(acc[i2][0], acc[i2][1], acc[i2][2], acc[i2][3]);
    }
}

// ---- aggregate layer1: one wave per node, lane = feature, 4-deep MLP -------
__global__ __launch_bounds__(256) void agg1_k(const int* __restrict__ csr,
                                              const int* __restrict__ row_start,
                                              const float* __restrict__ h1,
                                              const float* __restrict__ dinv,
                                              const float* __restrict__ b1,
                                              float* __restrict__ agg) {
    int n = blockIdx.x * 4 + (threadIdx.x >> 6);
    int lane = threadIdx.x & 63;
    if (n >= NN) return;
    int s0 = row_start[n], s1 = row_start[n + 1];
    float acc = 0.f, a0 = 0.f, a1 = 0.f, a2 = 0.f, a3 = 0.f;
    for (int j0 = s0; j0 < s1; j0 += 64) {
        int idx = j0 + lane;
        int sl = 0; float wl = 0.f;
        if (idx < s1) { sl = csr[idx]; wl = dinv[sl]; }
        int cnt = s1 - j0; if (cnt > 64) cnt = 64;
        int j = 0;
        for (; j + 4 <= cnt; j += 4) {
            int   sA = __shfl(sl, j + 0, 64), sB = __shfl(sl, j + 1, 64);
            int   sC = __shfl(sl, j + 2, 64), sD = __shfl(sl, j + 3, 64);
            float wA = __shfl(wl, j + 0, 64), wB = __shfl(wl, j + 1, 64);
            float wC = __shfl(wl, j + 2, 64), wD = __shfl(wl, j + 3, 64);
            float hA = h1[sA * FH + lane];
            float hB = h1[sB * FH + lane];
            float hC = h1[sC * FH + lane];
            float hD = h1[sD * FH + lane];
            a0 = fmaf(hA, wA, a0); a1 = fmaf(hB, wB, a1);
            a2 = fmaf(hC, wC, a2); a3 = fmaf(hD, wD, a3);
        }
        for (; j < cnt; j++) {
            int   s = __shfl(sl, j, 64);
            float w = __shfl(wl, j, 64);
            acc = fmaf(h1[s * FH + lane], w, acc);
        }
    }
    acc += (a0 + a1) + (a2 + a3);
    float dn = dinv[n];
    acc = fmaf(h1[n * FH + lane], dn, acc);
    agg[n * FH + lane] = fmaf(acc, dn, b1[lane]);
}

// ---- GEMM2 + relu: h2[NN][16] = relu(agg1) @ W2[64][16] -------------------
__global__ __launch_bounds__(192) void gemm2_k(const float* __restrict__ agg,
                                               const float* __restrict__ W2,
                                               float* __restrict__ h2) {
    __shared__ float a_lds[192 * 65];
    const int t = threadIdx.x;
    const int r0 = blockIdx.x * 192;
    #pragma unroll
    for (int i = 0; i < 16; i++) {
        int fidx = t + 192 * i;
        int row = fidx >> 4, kf = (fidx & 15) * 4;
        int gr = r0 + row;
        float4 v = make_float4(0.f, 0.f, 0.f, 0.f);
        if (gr < NN) v = *(const float4*)&agg[gr * FH + kf];
        v.x = fmaxf(v.x, 0.f); v.y = fmaxf(v.y, 0.f);
        v.z = fmaxf(v.z, 0.f); v.w = fmaxf(v.w, 0.f);
        a_lds[row * 65 + kf + 0] = v.x;
        a_lds[row * 65 + kf + 1] = v.y;
        a_lds[row * 65 + kf + 2] = v.z;
        a_lds[row * 65 + kf + 3] = v.w;
    }
    __syncthreads();
    float acc[FC] = {};
    #pragma unroll 4
    for (int k = 0; k < FH; k++) {
        float a = a_lds[t * 65 + k];
        #pragma unroll
        for (int c = 0; c < FC; c++)
            acc[c] = fmaf(a, W2[k * FC + c], acc[c]);
    }
    int r = r0 + t;
    if (r < NN) {
        #pragma unroll
        for (int q = 0; q < 4; q++)
            *(float4*)&h2[r * FC + 4 * q] =
                make_float4(acc[4*q], acc[4*q+1], acc[4*q+2], acc[4*q+3]);
    }
}

// ---- aggregate layer2: 16-lane subgroup per node, 4-deep MLP ---------------
__global__ __launch_bounds__(256) void agg2_k(const int* __restrict__ csr,
                                              const int* __restrict__ row_start,
                                              const float* __restrict__ h2,
                                              const float* __restrict__ dinv,
                                              const float* __restrict__ b2,
                                              float* __restrict__ out) {
    int n = blockIdx.x * 16 + (threadIdx.x >> 4);
    int l16 = threadIdx.x & 15;
    int base = threadIdx.x & 48;
    if (n >= NN) return;
    int s0 = row_start[n], s1 = row_start[n + 1];
    float acc = 0.f, a0 = 0.f, a1 = 0.f, a2 = 0.f, a3 = 0.f;
    for (int j0 = s0; j0 < s1; j0 += 16) {
        int idx = j0 + l16;
        int sl = 0; float wl = 0.f;
        if (idx < s1) { sl = csr[idx]; wl = dinv[sl]; }
        int cnt = s1 - j0; if (cnt > 16) cnt = 16;
        int j = 0;
        for (; j + 4 <= cnt; j += 4) {
            int   sA = __shfl(sl, base + j + 0, 64), sB = __shfl(sl, base + j + 1, 64);
            int   sC = __shfl(sl, base + j + 2, 64), sD = __shfl(sl, base + j + 3, 64);
            float wA = __shfl(wl, base + j + 0, 64), wB = __shfl(wl, base + j + 1, 64);
            float wC = __shfl(wl, base + j + 2, 64), wD = __shfl(wl, base + j + 3, 64);
            float hA = h2[sA * FC + l16];
            float hB = h2[sB * FC + l16];
            float hC = h2[sC * FC + l16];
            float hD = h2[sD * FC + l16];
            a0 = fmaf(hA, wA, a0); a1 = fmaf(hB, wB, a1);
            a2 = fmaf(hC, wC, a2); a3 = fmaf(hD, wD, a3);
        }
        for (; j < cnt; j++) {
            int   s = __shfl(sl, base + j, 64);
            float w = __shfl(wl, base + j, 64);
            acc = fmaf(h2[s * FC + l16], w, acc);
        }
    }
    acc += (a0 + a1) + (a2 + a3);
    float dn = dinv[n];
    acc = fmaf(h2[n * FC + l16], dn, acc);
    out[n * FC + l16] = fmaf(acc, dn, b2[l16]);
}

extern "C" void kernel_launch(void* const* d_in, const int* in_sizes, int n_in,
                              void* d_out, int out_size, void* d_ws, size_t ws_size,
                              hipStream_t stream) {
    const float* x  = (const float*)d_in[0];
    const int*   ei = (const int*)d_in[1];
    const float* W1 = (const float*)d_in[2];
    const float* b1 = (const float*)d_in[3];
    const float* W2 = (const float*)d_in[4];
    const float* b2 = (const float*)d_in[5];
    float* out = (float*)d_out;

    char* ws = (char*)d_ws;
    int*   deg       = (int*)(ws + 0);                       // 400 KB
    int*   row_start = (int*)(ws + 512 * 1024);              // 400 KB + 4
    float* dinv      = (float*)(ws + 1024 * 1024);           // 400 KB
    int*   flag      = (int*)(ws + 1536 * 1024);             // 4 B
    int*   partial   = (int*)(ws + 1540 * 1024);             // 392 B
    int*   csr       = (int*)(ws + 2ull * 1024 * 1024);      // 6.4 MB
    // packed (25.6 MB) aliases h1: fill_k finishes before gemm1_k writes h1.
    v4i*   packed    = (v4i*)(ws + 9ull * 1024 * 1024);      // 25.6 MB
    float* h1        = (float*)(ws + 9ull * 1024 * 1024);    // 25.6 MB
    float* agg1      = (float*)(ws + 35ull * 1024 * 1024);   // 25.6 MB
    float* h2        = h1;   // alias: h1 dead after agg1_k

    detect_k<<<1, 64, 0, stream>>>(ei, flag);
    (void)hipMemsetAsync(deg, 0, NN * sizeof(int), stream);
    count_k<<<(NE + 255) / 256, 256, 0, stream>>>(ei, flag, deg, packed);
    dinv_k<<<(NN + 255) / 256, 256, 0, stream>>>(deg, dinv);
    scan_sum_k<<<NB_SCAN, 256, 0, stream>>>(deg, partial);
    scan_part_k<<<1, 128, 0, stream>>>(partial);
    scan_out_k<<<NB_SCAN, 256, 0, stream>>>(deg, partial, row_start);
    for (int sw = 0; sw < NSWEEP; sw++)
        fill_k<<<(NE + 255) / 256, 256, 0, stream>>>(packed, row_start, csr,
                                                     sw * SWEEP_W, (sw + 1) * SWEEP_W);

    gemm1_k<<<(NN + 63) / 64, 256, 0, stream>>>(x, W1, h1);   // overwrites packed
    agg1_k<<<(NN + 3) / 4, 256, 0, stream>>>(csr, row_start, h1, dinv, b1, agg1);

    gemm2_k<<<(NN + 191) / 192, 192, 0, stream>>>(agg1, W2, h2);
    agg2_k<<<(NN + 15) / 16, 256, 0, stream>>>(csr, row_start, h2, dinv, b2, out);
}